// Round 13
// baseline (5760.647 us; speedup 1.0000x reference)
//
#include <hip/hip_runtime.h>
#include <hip/hip_bf16.h>

#define B_ 64
#define T_ 512
#define O_ 512
#define NWG 256
#define NTHR 256
#define EPSF 1e-5f

typedef __attribute__((ext_vector_type(8))) short short8v;
typedef __attribute__((ext_vector_type(4))) float f32x4;
typedef __attribute__((ext_vector_type(2))) float f32x2;
typedef unsigned short u16;
typedef unsigned int u32;
typedef unsigned long long u64;

__device__ __forceinline__ u16 f2bf(float f) {
    union { float f; u32 u; } v; v.f = f;
    u32 r = v.u + 0x7fffu + ((v.u >> 16) & 1u);   // RNE
    return (u16)(r >> 16);
}

// ---- sc1 (LLC-coherent, agent scope) helpers — relaxed, no fences, no RMW ----
__device__ __forceinline__ u32 ldg_sc1_u32(const u32* p) {
    return __hip_atomic_load(p, __ATOMIC_RELAXED, __HIP_MEMORY_SCOPE_AGENT);
}
__device__ __forceinline__ u64 ldg_sc1_u64(const void* p) {
    return __hip_atomic_load((const u64*)p, __ATOMIC_RELAXED, __HIP_MEMORY_SCOPE_AGENT);
}
__device__ __forceinline__ void stg_sc1_u32(u32* p, u32 v) {
    __hip_atomic_store(p, v, __ATOMIC_RELAXED, __HIP_MEMORY_SCOPE_AGENT);
}
__device__ __forceinline__ void stg_sc1_u64(u64* p, u64 v) {
    __hip_atomic_store(p, v, __ATOMIC_RELAXED, __HIP_MEMORY_SCOPE_AGENT);
}

// ---------- init: W fp32 [1024][2048] -> wt bf16 [2048 col][1024 k] ----------
__global__ void k_init_wt(const float* __restrict__ W, u16* __restrict__ wt) {
    __shared__ u16 tile[64][65];
    const int tk = (blockIdx.x >> 5) * 64;
    const int tn = (blockIdx.x & 31) * 64;
    const int r = threadIdx.x >> 6, c = threadIdx.x & 63;
#pragma unroll
    for (int i = 0; i < 16; ++i)
        tile[r + 4 * i][c] = f2bf(W[(size_t)(tk + r + 4 * i) * 2048 + tn + c]);
    __syncthreads();
#pragma unroll
    for (int i = 0; i < 16; ++i)
        wt[(size_t)(tn + r + 4 * i) * 1024 + tk + c] = tile[c][r + 4 * i];
}

__global__ void k_zero_flags(u32* grpfl) {
    int gid = blockIdx.x * 256 + threadIdx.x;
    if (gid < 512) stg_sc1_u32(grpfl + gid, 0u);
}

// ---------- persistent LN-LSTM: 8 static groups of 32 wgs, sc1 protocol ----------
// wg (grp=wgid&7, slot=wgid>>3): owns cols {512w + 16*slot + rl} (col-remap:
// wave w = gate w), processes batch rows grp*8..grp*8+8.  All cross-wg traffic:
// stats (2 KB, sc1) + h (8 KB, sc1-write / cached-read from rotating slots).
__global__ __launch_bounds__(NTHR, 1)
void k_persist(const float* __restrict__ x, const u16* __restrict__ wt,
               const float* __restrict__ bias, const float* __restrict__ lnw,
               const float* __restrict__ lnb, const float* __restrict__ hx,
               const float* __restrict__ cx, u16* hbuf, float* stats,
               u32* grpfl, float* __restrict__ out) {
    __shared__ float ldsC[4][8][17];   // [gate][row][16 outputs + pad]
    __shared__ f32x2 sp[4][8];         // per-wave (S,Q) partials per row
    __shared__ f32x2 sstat[8];         // final (S,Q) per row

    const int tid = threadIdx.x, wgid = blockIdx.x;
    const int grp = wgid & 7, slot = wgid >> 3;
    const int w = tid >> 6, l = tid & 63;
    const int rl = l & 15, kg = l >> 4;
    const int arow = rl & 7;                   // A-row (0..7) this lane loads

    u16* grp_h0 = hbuf + grp * 8 * 512;        // group's rows within a slot
    float* grp_s = stats + grp * 512;          // 8 rows x 32 slots x (S,Q)
    u32* gf = grpfl + grp * 64;                // 32 slot flags (256 B region)

    // ---- W fragments into registers (16 cols x full K per wave) ----
    const int mycol = 512 * w + 16 * slot + rl;
    short8v bw[32];
#pragma unroll
    for (int kc = 0; kc < 32; ++kc)
        bw[kc] = *(const short8v*)(wt + (size_t)mycol * 1024 + kc * 32 + kg * 8);
    const float bcol = bias[mycol];

    // ---- phase-2 identity: tid<128 -> (row pb, output po) ----
    const int pb = tid >> 4, pi = tid & 15;
    const int po = 16 * slot + pi;
    float lw0 = 0.f, lw1 = 0.f, lw2 = 0.f, lw3 = 0.f;
    float lb0 = 0.f, lb1 = 0.f, lb2 = 0.f, lb3 = 0.f, creg = 0.f;
    if (tid < 128) {
        lw0 = lnw[po]; lw1 = lnw[512 + po]; lw2 = lnw[1024 + po]; lw3 = lnw[1536 + po];
        lb0 = lnb[po]; lb1 = lnb[512 + po]; lb2 = lnb[1024 + po]; lb3 = lnb[1536 + po];
        creg = cx[po];
        float h0 = hx[po];
        float hn = __shfl_xor(h0, 1);
        if (!(pi & 1)) {                       // h0 into rotating slot 0 (sc1)
            u32 hp = (u32)f2bf(h0) | ((u32)f2bf(hn) << 16);
            stg_sc1_u32((u32*)(grp_h0 + pb * 512 + po), hp);
        }
    }

    // ---- group barrier: distinct-word sc1 flags, one wave polls ----
    auto g_arrive = [&](u32 g) {
        asm volatile("s_waitcnt vmcnt(0)" ::: "memory");   // sc1 stores at LLC
        __syncthreads();
        if (tid == 0) stg_sc1_u32(gf + slot, g);
    };
    auto g_wait = [&](u32 g) {
        if (tid < 32) {
            while (!__all(ldg_sc1_u32(gf + tid) >= g)) {}
        }
        __syncthreads();
    };

    // ---- x-half GEMM: fp32 cached loads + convert, K 0..511 ----
    auto xgemm = [&](int t, f32x4& c0, f32x4& c1) {
        const float* xr = x + (size_t)(grp * 8 + arow) * (T_ * 512) + (size_t)t * 512;
#pragma unroll
        for (int kc = 0; kc < 16; ++kc) {
            float4 u0 = *(const float4*)(xr + kc * 32 + kg * 8);
            float4 u1 = *(const float4*)(xr + kc * 32 + kg * 8 + 4);
            short8v a;
            a[0] = (short)f2bf(u0.x); a[1] = (short)f2bf(u0.y);
            a[2] = (short)f2bf(u0.z); a[3] = (short)f2bf(u0.w);
            a[4] = (short)f2bf(u1.x); a[5] = (short)f2bf(u1.y);
            a[6] = (short)f2bf(u1.z); a[7] = (short)f2bf(u1.w);
            if (kc & 1) c1 = __builtin_amdgcn_mfma_f32_16x16x32_bf16(a, bw[kc], c1, 0, 0, 0);
            else        c0 = __builtin_amdgcn_mfma_f32_16x16x32_bf16(a, bw[kc], c0, 0, 0, 0);
        }
    };

    f32x4 xa0 = {0.f, 0.f, 0.f, 0.f}, xa1 = {0.f, 0.f, 0.f, 0.f};
    g_arrive(1);
    xgemm(0, xa0, xa1);
    g_wait(1);

    for (int t = 0; t < T_; ++t) {
        const u32 genA = 2 + 2 * t, genB = 3 + 2 * t;

        // ===== phase 1: h-half GEMM (K 512..1023), PLAIN CACHED loads from
        //       the rotating slot t (virgin addresses -> no staleness; XCD L2
        //       amortizes the 8 KB across all co-located wgs) =====
        {
            const u16* hrow = hbuf + (size_t)t * (B_ * O_) + (size_t)(grp * 8 + arow) * 512;
#pragma unroll
            for (int kc = 0; kc < 16; ++kc) {
                short8v a = *(const short8v*)(hrow + kc * 32 + kg * 8);
                if (kc & 1) xa1 = __builtin_amdgcn_mfma_f32_16x16x32_bf16(a, bw[16 + kc], xa1, 0, 0, 0);
                else        xa0 = __builtin_amdgcn_mfma_f32_16x16x32_bf16(a, bw[16 + kc], xa0, 0, 0, 0);
            }
        }
        f32x4 acc = xa0 + xa1;

        // comb stays local: LDS for the gate combine + shfl stats partials
        float v4[4], sj[4], qj[4];
#pragma unroll
        for (int j = 0; j < 4; ++j) {
            v4[j] = acc[j] + bcol;
            sj[j] = v4[j]; qj[j] = v4[j] * v4[j];
        }
        if (kg < 2) {
#pragma unroll
            for (int j = 0; j < 4; ++j) ldsC[w][kg * 4 + j][rl] = v4[j];
        }
#pragma unroll
        for (int m = 1; m < 16; m <<= 1) {
#pragma unroll
            for (int j = 0; j < 4; ++j) {
                sj[j] += __shfl_xor(sj[j], m);
                qj[j] += __shfl_xor(qj[j], m);
            }
        }
        if (rl == 0 && kg < 2) {
#pragma unroll
            for (int j = 0; j < 4; ++j) sp[w][kg * 4 + j] = f32x2{sj[j], qj[j]};
        }
        __syncthreads();
        if (tid < 8) {            // one (S,Q) per row per wg -> sc1
            float S = sp[0][tid].x + sp[1][tid].x + sp[2][tid].x + sp[3][tid].x;
            float Q = sp[0][tid].y + sp[1][tid].y + sp[2][tid].y + sp[3][tid].y;
            union { float f[2]; u64 q; } uu; uu.f[0] = S; uu.f[1] = Q;
            stg_sc1_u64((u64*)(grp_s + (tid * 32 + slot) * 2), uu.q);
        }
        asm volatile("s_waitcnt vmcnt(0)" ::: "memory");
        if (tid == 0) stg_sc1_u32(gf + slot, genA);

        // prefetch x-half of t+1 under the barrier-A wait
        if (t + 1 < T_) {
            xa0 = f32x4{0.f, 0.f, 0.f, 0.f}; xa1 = f32x4{0.f, 0.f, 0.f, 0.f};
            xgemm(t + 1, xa0, xa1);
        }
        g_wait(genA);

        // ===== phase 2: stats reduce + LN + gates + state =====
        {
            f32x2 pv;
            union { u64 q; float f[2]; } uu;
            uu.q = ldg_sc1_u64(grp_s + ((size_t)(tid >> 5) * 32 + (tid & 31)) * 2);
            pv.x = uu.f[0]; pv.y = uu.f[1];
            float s = pv.x, q = pv.y;
#pragma unroll
            for (int m = 1; m < 32; m <<= 1) {
                s += __shfl_xor(s, m);
                q += __shfl_xor(q, m);
            }
            if ((tid & 31) == 0) sstat[tid >> 5] = f32x2{s, q};
        }
        __syncthreads();

        if (tid < 128) {
            float S = sstat[pb].x, Q = sstat[pb].y;
            float mu = S * (1.0f / 2048.0f);
            float var = Q * (1.0f / 2048.0f) - mu * mu;
            float rstd = rsqrtf(var + EPSF);
            float g0 = (ldsC[0][pb][pi] - mu) * rstd * lw0 + lb0;
            float g1 = (ldsC[1][pb][pi] - mu) * rstd * lw1 + lb1;
            float g2 = (ldsC[2][pb][pi] - mu) * rstd * lw2 + lb2;
            float g3 = (ldsC[3][pb][pi] - mu) * rstd * lw3 + lb3;
            float ig = 1.f / (1.f + __expf(-g0));
            float fg = 1.f / (1.f + __expf(-g1));
            float og = 1.f / (1.f + __expf(-g2));
            float e2 = __expf(-2.f * fabsf(g3));
            float th = copysignf((1.f - e2) / (1.f + e2), g3);
            creg = fg * creg + ig * th;
            float h = og * creg;
            __builtin_nontemporal_store(h,
                out + (size_t)(grp * 8 + pb) * (T_ * O_) + (size_t)t * O_ + po);
            if (t + 1 < T_) {     // h(t+1) into the FRESH rotating slot (sc1)
                float hn = __shfl_xor(h, 1);
                if (!(pi & 1)) {
                    u32 hp = (u32)f2bf(h) | ((u32)f2bf(hn) << 16);
                    stg_sc1_u32((u32*)(hbuf + (size_t)(t + 1) * (B_ * O_)
                                       + (size_t)(grp * 8 + pb) * 512 + po), hp);
                }
            }
        }

        if (t == T_ - 1) break;
        g_arrive(genB);
        g_wait(genB);
    }
}

extern "C" void kernel_launch(void* const* d_in, const int* in_sizes, int n_in,
                              void* d_out, int out_size, void* d_ws, size_t ws_size,
                              hipStream_t stream) {
    const float* x    = (const float*)d_in[0];
    const float* W    = (const float*)d_in[1];
    const float* bias = (const float*)d_in[2];
    const float* lnw  = (const float*)d_in[3];
    const float* lnb  = (const float*)d_in[4];
    const float* hx   = (const float*)d_in[5];
    const float* cx   = (const float*)d_in[6];
    float* out = (float*)d_out;

    char* ws = (char*)d_ws;
    u16*   wt    = (u16*)ws;                      // 4 MiB
    u16*   hbuf  = (u16*)(ws + 4194304);          // 32 MiB (512 rotating h slots)
    float* stats = (float*)(ws + 37748736);       // 16 KiB (8 grp x 2 KiB)
    u32*   grpfl = (u32*)(ws + 37765120);         // 2 KiB (8 grp x 64 u32)
    // total ~36.02 MiB < proven 38.79 MiB budget (r4)

    k_init_wt<<<512, 256, 0, stream>>>(W, wt);
    k_zero_flags<<<2, 256, 0, stream>>>(grpfl);
    k_persist<<<NWG, NTHR, 0, stream>>>(x, wt, bias, lnw, lnb, hx, cx,
                                        hbuf, stats, grpfl, out);
}

// Round 15
// 3669.054 us; speedup vs baseline: 1.5701x; 1.5701x over previous
//
#include <hip/hip_runtime.h>
#include <hip/hip_bf16.h>

#define B_ 64
#define T_ 512
#define O_ 512
#define NWG 256
#define NTHR 256
#define EPSF 1e-5f

typedef __attribute__((ext_vector_type(8))) short short8v;
typedef __attribute__((ext_vector_type(4))) float f32x4;
typedef __attribute__((ext_vector_type(2))) float f32x2;
typedef unsigned short u16;
typedef unsigned int u32;
typedef unsigned long long u64;

__device__ __forceinline__ u16 f2bf(float f) {
    union { float f; u32 u; } v; v.f = f;
    u32 r = v.u + 0x7fffu + ((v.u >> 16) & 1u);   // RNE
    return (u16)(r >> 16);
}
__device__ __forceinline__ float bf2f(u16 h) {
    union { u32 u; float f; } v; v.u = ((u32)h) << 16; return v.f;
}

// ---- sc1 (LLC-coherent, agent scope) helpers — relaxed, no fences, no RMW ----
__device__ __forceinline__ u32 ldg_sc1_u32(const u32* p) {
    return __hip_atomic_load(p, __ATOMIC_RELAXED, __HIP_MEMORY_SCOPE_AGENT);
}
__device__ __forceinline__ u64 ldg_sc1_u64(const void* p) {
    return __hip_atomic_load((const u64*)p, __ATOMIC_RELAXED, __HIP_MEMORY_SCOPE_AGENT);
}
__device__ __forceinline__ void stg_sc1_u32(u32* p, u32 v) {
    __hip_atomic_store(p, v, __ATOMIC_RELAXED, __HIP_MEMORY_SCOPE_AGENT);
}
__device__ __forceinline__ void stg_sc1_u64(u64* p, u64 v) {
    __hip_atomic_store(p, v, __ATOMIC_RELAXED, __HIP_MEMORY_SCOPE_AGENT);
}

// ---------- init: W fp32 [1024][2048] -> wt bf16 [2048 col][1024 k] ----------
__global__ void k_init_wt(const float* __restrict__ W, u16* __restrict__ wt) {
    __shared__ u16 tile[64][65];
    const int tk = (blockIdx.x >> 5) * 64;
    const int tn = (blockIdx.x & 31) * 64;
    const int r = threadIdx.x >> 6, c = threadIdx.x & 63;
#pragma unroll
    for (int i = 0; i < 16; ++i)
        tile[r + 4 * i][c] = f2bf(W[(size_t)(tk + r + 4 * i) * 2048 + tn + c]);
    __syncthreads();
#pragma unroll
    for (int i = 0; i < 16; ++i)
        wt[(size_t)(tn + r + 4 * i) * 1024 + tk + c] = tile[c][r + 4 * i];
}

// ---------- init: x fp32 [b][t][k] -> xbf bf16 [t][b][k] ----------
__global__ void k_init_x(const float* __restrict__ x, u16* __restrict__ xbf) {
    size_t e = ((size_t)blockIdx.x * 256 + threadIdx.x) * 8;
    int b = (int)(e >> 18);
    int r = (int)(e & 262143);
    int t = r >> 9, k = r & 511;
    float4 u0 = *(const float4*)(x + e);
    float4 u1 = *(const float4*)(x + e + 4);
    short8v v;
    v[0] = (short)f2bf(u0.x); v[1] = (short)f2bf(u0.y);
    v[2] = (short)f2bf(u0.z); v[3] = (short)f2bf(u0.w);
    v[4] = (short)f2bf(u1.x); v[5] = (short)f2bf(u1.y);
    v[6] = (short)f2bf(u1.z); v[7] = (short)f2bf(u1.w);
    *(short8v*)(xbf + ((size_t)t * B_ + b) * 512 + k) = v;
}

__global__ void k_zero_flags(u32* grpfl) {
    int gid = blockIdx.x * 256 + threadIdx.x;
    if (gid < 512) stg_sc1_u32(grpfl + gid, 0u);
}

// ---------- persistent LN-LSTM: 8 groups x 32 wgs, ONE barrier/step ----------
// wg (grp=wgid&7, slot=wgid>>3) owns cols {512w+16slot+rl} (wave w = gate w),
// batch rows grp*8..+8.  Per step: GEMM -> comb slice (bf16 pairs) + stats
// partial (sc1, parity-double-buffered) -> barrier -> every wg gathers its
// group's comb rows + stats and REDUNDANTLY computes gates/c/h for its 8 rows
// -> h straight into own LDS tile for next step's h-GEMM.  h never crosses
// memory; one barrier per step.
__global__ __launch_bounds__(NTHR, 1)
void k_persist(const u16* __restrict__ xbf, const u16* __restrict__ wt,
               const float* __restrict__ bias, const float* __restrict__ lnw,
               const float* __restrict__ lnb, const float* __restrict__ hx,
               const float* __restrict__ cx, u32* comb, float* statsp,
               u32* grpfl, float* __restrict__ out) {
    __shared__ u16 hT[4096];          // [8 rows][512] bf16, XOR-swizzled (G4)
    __shared__ f32x2 sp[4][8];        // per-wave (S,Q) partials per row
    __shared__ f32x2 sstat[8];        // reduced (S,Q) per row

    const int tid = threadIdx.x, wgid = blockIdx.x;
    const int grp = wgid & 7, slot = wgid >> 3;
    const int w = tid >> 6, l = tid & 63;
    const int rl = l & 15, kg = l >> 4;
    const int arow = rl & 7;                    // A-row this lane loads
    char* hTB = (char*)hT;
    u32* gf = grpfl + grp * 64;                 // 32 slot flags per group

    // ---- W fragments into registers (16 cols x full K per wave) ----
    const int mycol = 512 * w + 16 * slot + rl;
    short8v bw[32];
#pragma unroll
    for (int kc = 0; kc < 32; ++kc)
        bw[kc] = *(const short8v*)(wt + (size_t)mycol * 1024 + kc * 32 + kg * 8);
    const float bcol = bias[mycol];

    // ---- gate-lane identity: thread owns outputs {po2, po2+1} for ALL 8 rows ----
    const int po2 = tid * 2;
    float lwv[8], lbv[8];
#pragma unroll
    for (int g = 0; g < 4; ++g) {
        lwv[g * 2]     = lnw[g * 512 + po2];
        lwv[g * 2 + 1] = lnw[g * 512 + po2 + 1];
        lbv[g * 2]     = lnb[g * 512 + po2];
        lbv[g * 2 + 1] = lnb[g * 512 + po2 + 1];
    }
    float c16[16];
    {
        float c0 = cx[po2], c1 = cx[po2 + 1];
#pragma unroll
        for (int r = 0; r < 8; ++r) { c16[r * 2] = c0; c16[r * 2 + 1] = c1; }
        u32 hp = (u32)f2bf(hx[po2]) | ((u32)f2bf(hx[po2 + 1]) << 16);
#pragma unroll
        for (int r = 0; r < 8; ++r)                  // h0 (same for all rows)
            *(u32*)(hTB + ((r * 1024 + po2 * 2) ^ (r << 4))) = hp;
    }
    __syncthreads();

    // ---- single group barrier per step (r9-proven protocol) ----
    auto g_arrive = [&](u32 g) {
        asm volatile("s_waitcnt vmcnt(0)" ::: "memory");
        __syncthreads();
        if (tid == 0) stg_sc1_u32(gf + slot, g);
    };
    auto g_wait = [&](u32 g) {
        if (tid < 32) { while (!__all(ldg_sc1_u32(gf + tid) >= g)) {} }
        __syncthreads();
    };

    // ---- x-half GEMM: bf16 cached loads, K 0..511 ----
    auto xgemm = [&](int t, f32x4& c0, f32x4& c1) {
        const u16* xr = xbf + ((size_t)t * B_ + grp * 8 + arow) * 512;
#pragma unroll
        for (int kc = 0; kc < 16; ++kc) {
            short8v a = *(const short8v*)(xr + kc * 32 + kg * 8);
            if (kc & 1) c1 = __builtin_amdgcn_mfma_f32_16x16x32_bf16(a, bw[kc], c1, 0, 0, 0);
            else        c0 = __builtin_amdgcn_mfma_f32_16x16x32_bf16(a, bw[kc], c0, 0, 0, 0);
        }
    };

    f32x4 xa0 = {0.f, 0.f, 0.f, 0.f}, xa1 = {0.f, 0.f, 0.f, 0.f};
    xgemm(0, xa0, xa1);

    for (int t = 0; t < T_; ++t) {
        // ===== phase 1: h-half GEMM from own LDS (swizzled b128 reads) =====
#pragma unroll
        for (int kc = 0; kc < 16; ++kc) {
            int byte = arow * 1024 + kc * 64 + kg * 16;
            short8v a = *(const short8v*)(hTB + (byte ^ (arow << 4)));
            if (kc & 1) xa1 = __builtin_amdgcn_mfma_f32_16x16x32_bf16(a, bw[16 + kc], xa1, 0, 0, 0);
            else        xa0 = __builtin_amdgcn_mfma_f32_16x16x32_bf16(a, bw[16 + kc], xa0, 0, 0, 0);
        }
        f32x4 acc = xa0 + xa1;

        const int cb = t & 1;                       // parity double buffer
        u32*   combB = comb + (size_t)cb * (64 * 1024);        // bf16 pairs
        float* statB = statsp + (size_t)cb * (64 * 32 * 2);

        float v4[4], vo[4], sj[4], qj[4];
#pragma unroll
        for (int j = 0; j < 4; ++j) {
            v4[j] = acc[j] + bcol;
            sj[j] = v4[j]; qj[j] = v4[j] * v4[j];
        }
#pragma unroll
        for (int j = 0; j < 4; ++j) vo[j] = __shfl_xor(v4[j], 1);   // col-pair mate
#pragma unroll
        for (int m = 1; m < 16; m <<= 1) {
#pragma unroll
            for (int j = 0; j < 4; ++j) {
                sj[j] += __shfl_xor(sj[j], m);
                qj[j] += __shfl_xor(qj[j], m);
            }
        }
        if (kg < 2) {                               // rows 0..7 (kg>=2 duplicates)
            if (!(rl & 1)) {                        // even col stores the pair
#pragma unroll
                for (int j = 0; j < 4; ++j) {
                    u32 pk = (u32)f2bf(v4[j]) | ((u32)f2bf(vo[j]) << 16);
                    stg_sc1_u32(combB + ((size_t)(grp * 8 + kg * 4 + j) * 1024
                                         + w * 256 + slot * 8 + (rl >> 1)), pk);
                }
            }
            if (rl == 0) {
#pragma unroll
                for (int j = 0; j < 4; ++j) sp[w][kg * 4 + j] = f32x2{sj[j], qj[j]};
            }
        }
        __syncthreads();
        if (tid < 8) {                              // one (S,Q) per row per wg
            float S = sp[0][tid].x + sp[1][tid].x + sp[2][tid].x + sp[3][tid].x;
            float Q = sp[0][tid].y + sp[1][tid].y + sp[2][tid].y + sp[3][tid].y;
            union { float f[2]; u64 q; } uu; uu.f[0] = S; uu.f[1] = Q;
            stg_sc1_u64((u64*)(statB + ((size_t)(grp * 8 + tid) * 32 + slot) * 2), uu.q);
        }

        g_arrive(t + 1);                            // THE one barrier per step
        if (t + 1 < T_) {                           // overlap: x-GEMM of t+1
            xa0 = f32x4{0.f, 0.f, 0.f, 0.f}; xa1 = f32x4{0.f, 0.f, 0.f, 0.f};
            xgemm(t + 1, xa0, xa1);
        }
        g_wait(t + 1);

        // ===== phase 2 (redundant per wg): gather comb rows + stats, gates =====
        u32 cgf[8][4];
#pragma unroll
        for (int r = 0; r < 8; ++r) {
#pragma unroll
            for (int g = 0; g < 4; ++g)
                cgf[r][g] = ldg_sc1_u32(combB + ((size_t)(grp * 8 + r) * 1024
                                                 + g * 256 + tid));
        }
        {
            union { u64 q; float f[2]; } uu;
            uu.q = ldg_sc1_u64(statB + ((size_t)(grp * 8 + (tid >> 5)) * 32 + (tid & 31)) * 2);
            float s = uu.f[0], q = uu.f[1];
#pragma unroll
            for (int m = 1; m < 32; m <<= 1) {
                s += __shfl_xor(s, m);
                q += __shfl_xor(q, m);
            }
            if ((tid & 31) == 0) sstat[tid >> 5] = f32x2{s, q};
        }
        __syncthreads();

#pragma unroll
        for (int r = 0; r < 8; ++r) {
            float S = sstat[r].x, Q = sstat[r].y;
            float mu = S * (1.0f / 2048.0f);
            float var = Q * (1.0f / 2048.0f) - mu * mu;
            float rstd = rsqrtf(var + EPSF);
            float hh[2];
#pragma unroll
            for (int i = 0; i < 2; ++i) {
                float cv0 = bf2f((u16)(cgf[r][0] >> (16 * i)));
                float cv1 = bf2f((u16)(cgf[r][1] >> (16 * i)));
                float cv2 = bf2f((u16)(cgf[r][2] >> (16 * i)));
                float cv3 = bf2f((u16)(cgf[r][3] >> (16 * i)));
                float g0 = (cv0 - mu) * rstd * lwv[0 + i] + lbv[0 + i];
                float g1 = (cv1 - mu) * rstd * lwv[2 + i] + lbv[2 + i];
                float g2 = (cv2 - mu) * rstd * lwv[4 + i] + lbv[4 + i];
                float g3 = (cv3 - mu) * rstd * lwv[6 + i] + lbv[6 + i];
                float ig = 1.f / (1.f + __expf(-g0));
                float fg = 1.f / (1.f + __expf(-g1));
                float og = 1.f / (1.f + __expf(-g2));
                float e2 = __expf(-2.f * fabsf(g3));
                float th = copysignf((1.f - e2) / (1.f + e2), g3);
                float cc = fg * c16[r * 2 + i] + ig * th;
                c16[r * 2 + i] = cc;
                hh[i] = og * cc;
            }
            u32 hp = (u32)f2bf(hh[0]) | ((u32)f2bf(hh[1]) << 16);
            *(u32*)(hTB + ((r * 1024 + po2 * 2) ^ (r << 4))) = hp;   // h(t+1) tile
            if (slot == 0) {                        // one wg per group writes out
                f32x2 ho{hh[0], hh[1]};
                __builtin_nontemporal_store(ho,
                    (f32x2*)(out + (size_t)(grp * 8 + r) * (T_ * O_) + (size_t)t * O_ + po2));
            }
        }
        __syncthreads();                            // hT ready for next h-GEMM
    }
}

extern "C" void kernel_launch(void* const* d_in, const int* in_sizes, int n_in,
                              void* d_out, int out_size, void* d_ws, size_t ws_size,
                              hipStream_t stream) {
    const float* x    = (const float*)d_in[0];
    const float* W    = (const float*)d_in[1];
    const float* bias = (const float*)d_in[2];
    const float* lnw  = (const float*)d_in[3];
    const float* lnb  = (const float*)d_in[4];
    const float* hx   = (const float*)d_in[5];
    const float* cx   = (const float*)d_in[6];
    float* out = (float*)d_out;

    char* ws = (char*)d_ws;
    u16*   wt     = (u16*)ws;                     // [0        .. 4194304)
    u16*   xbf    = (u16*)(ws + 4194304);         // [4194304  .. 37748736)
    u32*   comb   = (u32*)(ws + 37748736);        // [37748736 .. 38273024)  512 KiB
    float* statsp = (float*)(ws + 38273024);      // [38273024 .. 38305792)   32 KiB
    u32*   grpfl  = (u32*)(ws + 38305792);        // [38305792 .. 38307840)    2 KiB
    // total 38307840 B < 38797312 B proven budget (r4); regions disjoint.

    k_init_wt<<<512, 256, 0, stream>>>(W, wt);
    k_init_x<<<8192, 256, 0, stream>>>(x, xbf);
    k_zero_flags<<<2, 256, 0, stream>>>(grpfl);
    k_persist<<<NWG, NTHR, 0, stream>>>(xbf, wt, bias, lnw, lnb, hx, cx,
                                        comb, statsp, grpfl, out);
}